// Round 6
// baseline (251.928 us; speedup 1.0000x reference)
//
#include <hip/hip_runtime.h>

// RGCN: N=50000, E=1.6M, R=8, 128 -> 64 -> 64.
// R18 = R17 (245.3us) + occupancy fix for the 53us fused kernel:
//   - append CH 4096->2048: stage 16KB, LDS 22.7KB, 782 append blocks;
//     per-thread 8 edges held in REGISTERS across passes (src/dst/et read
//     once, not twice); bucket id stored in stage[].y directly.
//   - gemm B-dbuf -> SINGLE buffer (breg prefetch already covers the
//     overlap): K=128 LDS 34.8->17.4KB. Dispatch LDS max = 22.7KB
//     -> 7 blocks/CU (was 4), 1564-block grid ~fully co-resident.
//   - gemm_l2 single-buffer too (9.2KB).
//   - kept: rel-major xw, swapped-MFMA vector epilogue, bf16 hroot,
//     unconditional clamped 8-slot agg, fused append||gemm1 odd/even.

constexpr int NN  = 50000;
constexpr int NE  = 1600000;
constexpr int NR  = 8;
constexpr int FIN = 128;
constexpr int FH  = 64;

constexpr int BSH = 7;                       // 128 dst nodes per bucket
constexpr int BN  = 1 << BSH;
constexpr int NB  = (NN + BN - 1) >> BSH;    // 391
constexpr int CAP = 6144;                    // bucket capacity (load ~4092±64)
constexpr int CH  = 2048;                    // edges per append block
constexpr int NAPP = (NE + CH - 1) / CH;     // 782 append blocks
constexpr int APPLDS = CH * 8 + 4 * NB * 4 + 16;   // 22656 B

typedef __attribute__((ext_vector_type(8))) short bf16x8;
typedef __attribute__((ext_vector_type(4))) short bf16x4;
typedef __attribute__((ext_vector_type(4))) float f32x4;

__device__ __forceinline__ unsigned short f2bf(float f) {
  unsigned u = __float_as_uint(f);
  u = (u + 0x7fff + ((u >> 16) & 1)) >> 16;   // RNE
  return (unsigned short)u;
}
__device__ __forceinline__ float bf2f(unsigned short b) {
  return __uint_as_float(((unsigned)b) << 16);
}
__device__ __forceinline__ bool edge_ok(unsigned s, unsigned d, unsigned r) {
  return s < NN && d < NN && r < NR;
}

// ---------------- CSR build: append (device body, LDS via pointer) ----------
// LDS: stage[CH] uint2 (16384B) | h[NB] | gbase[NB] | sbase[NB] | scur[NB] |
// wtot[4] = 22656 B. Each thread owns CH/256 = 8 edges, held in registers.
__device__ void append_body(char* smem, int bx,
                            const int* __restrict__ src,
                            const int* __restrict__ dst,
                            const int* __restrict__ et,
                            int* __restrict__ bcur,
                            unsigned* __restrict__ brecs) {
  uint2* stage = (uint2*)smem;
  int* h     = (int*)(smem + (size_t)CH * 8);
  int* gbase = h + NB;
  int* sbase = gbase + NB;
  int* scur  = sbase + NB;
  int* wtot  = scur + NB;

  const int t  = threadIdx.x;
  const int c0 = bx * CH;
  const int m  = min(CH, NE - c0);

  for (int i = t; i < NB; i += 256) h[i] = 0;

  // load this thread's 8 edges into registers (read once)
  unsigned rex[8], bux[8];
#pragma unroll
  for (int k = 0; k < 8; ++k) {
    const int i = t + k * 256;
    bux[k] = 0xFFFFFFFFu;
    if (i < m) {
      const unsigned sv = (unsigned)src[c0 + i];
      const unsigned d  = (unsigned)dst[c0 + i];
      const unsigned r  = (unsigned)et[c0 + i];
      if (edge_ok(sv, d, r)) {
        rex[k] = (sv << 10) | ((d & (BN - 1)) << 3) | r;
        bux[k] = d >> BSH;
      }
    }
  }
  __syncthreads();

  // pass A: per-block bucket histogram
#pragma unroll
  for (int k = 0; k < 8; ++k)
    if (bux[k] != 0xFFFFFFFFu) atomicAdd(&h[bux[k]], 1);
  __syncthreads();

  // reserve spans + block-local exclusive scan (2 buckets per thread)
  const int v0 = (2 * t < NB) ? h[2 * t] : 0;
  const int v1 = (2 * t + 1 < NB) ? h[2 * t + 1] : 0;
  if (2 * t < NB     && v0) gbase[2 * t]     = atomicAdd(&bcur[2 * t], v0);
  if (2 * t + 1 < NB && v1) gbase[2 * t + 1] = atomicAdd(&bcur[2 * t + 1], v1);
  const int s = v0 + v1;
  int incl = s;
#pragma unroll
  for (int o = 1; o < 64; o <<= 1) {
    int u = __shfl_up(incl, o, 64);
    if ((t & 63) >= o) incl += u;
  }
  if ((t & 63) == 63) wtot[t >> 6] = incl;
  __syncthreads();
  int wo = 0;
  for (int w = 0; w < (t >> 6); ++w) wo += wtot[w];
  const int e = wo + incl - s;
  if (2 * t < NB)     { sbase[2 * t] = e;          scur[2 * t] = e; }
  if (2 * t + 1 < NB) { sbase[2 * t + 1] = e + v0; scur[2 * t + 1] = e + v0; }
  __syncthreads();

  // pass B: stage records grouped by bucket (bucket id kept in .y)
#pragma unroll
  for (int k = 0; k < 8; ++k) {
    if (bux[k] != 0xFFFFFFFFu) {
      const int p = atomicAdd(&scur[bux[k]], 1);
      if (p < CH) stage[p] = make_uint2(rex[k], bux[k]);
    }
  }
  __syncthreads();

  // write-out: consecutive j -> consecutive global addresses (4B packed)
  const int M = min(sbase[NB - 1] + h[NB - 1], CH);
  for (int j = t; j < M; j += 256) {
    const uint2 rec = stage[j];
    const int b = (int)rec.y;
    const int idx = min(gbase[b] + (j - sbase[b]), NB * CAP - 1);
    brecs[idx] = rec.x;
  }
}

// ---------------- CSR build: finalize ----------------
// Final record: cnt<<25 | addr, addr = (r*NN+sv)*64 (rel-major xw offset,
// max 25599936 < 2^25). Weight 1/cnt via v_rcp in agg.
__global__ void __launch_bounds__(256) bucket_finalize(
    const int* __restrict__ bcur, const unsigned* __restrict__ brecs,
    int* __restrict__ row_start, int* __restrict__ deg,
    unsigned* __restrict__ recs) {
  const int b    = blockIdx.x;
  const int base = b * CAP;
  const int m    = min(bcur[b] - base, CAP);
  const int d0   = b << BSH;
  __shared__ int cnt[BN * NR];
  __shared__ int curs[BN * NR];
  __shared__ int wtot[4];
  const int t = threadIdx.x;

  for (int i = t; i < BN * NR; i += 256) cnt[i] = 0;
  __syncthreads();
  for (int i = t; i < m; i += 256) {
    const unsigned rec = brecs[base + i];
    const int dl = (int)((rec >> 3) & (BN - 1));
    const int r  = (int)(rec & 7);
    atomicAdd(&cnt[dl * NR + r], 1);
  }
  __syncthreads();

  const int c0 = cnt[t * 4], c1 = cnt[t * 4 + 1], c2 = cnt[t * 4 + 2], c3 = cnt[t * 4 + 3];
  const int s = c0 + c1 + c2 + c3;
  int incl = s;
#pragma unroll
  for (int o = 1; o < 64; o <<= 1) {
    int u = __shfl_up(incl, o, 64);
    if ((t & 63) >= o) incl += u;
  }
  if ((t & 63) == 63) wtot[t >> 6] = incl;
  __syncthreads();
  int wo = 0;
  for (int w = 0; w < (t >> 6); ++w) wo += wtot[w];
  const int e = wo + incl - s;
  curs[t * 4]     = e;
  curs[t * 4 + 1] = e + c0;
  curs[t * 4 + 2] = e + c0 + c1;
  curs[t * 4 + 3] = e + c0 + c1 + c2;
  __syncthreads();

  if (t < BN) {
    const int d = d0 + t;
    if (d < NN) {
      const int start = curs[t * NR];
      const int end   = (t == BN - 1) ? m : curs[(t + 1) * NR];
      row_start[d] = base + start;
      deg[d]       = end - start;
    }
  }
  __syncthreads();

  for (int i = t; i < m; i += 256) {
    const unsigned rec = brecs[base + i];
    const int dl = (int)((rec >> 3) & (BN - 1));
    const int r  = (int)(rec & 7);
    const unsigned sv = rec >> 10;
    const int p  = atomicAdd(&curs[dl * NR + r], 1);
    const unsigned cn = (unsigned)min(cnt[dl * NR + r], 127);
    recs[base + min(p, CAP - 1)] = (cn << 25) | (((unsigned)r * NN + sv) << 6);
  }
}

// ---------------- prep: bcur init + weights -> bf16 transposed ----------------
__global__ void prep(const float* __restrict__ W1r, const float* __restrict__ W1o,
                     const float* __restrict__ W2r, const float* __restrict__ W2o,
                     unsigned short* __restrict__ Wt1,
                     unsigned short* __restrict__ Wt2,
                     int* __restrict__ bcur) {
  const int i  = blockIdx.x * blockDim.x + threadIdx.x;
  if (i < NB) bcur[i] = i * CAP;
  const int n1 = (NR + 1) * 64 * FIN;
  const int n2 = (NR + 1) * 64 * FH;
  if (i < n1) {
    const int g = i / (64 * FIN), rem = i % (64 * FIN);
    const int n = rem / FIN, k = rem % FIN;
    const float* W = (g < NR) ? (W1r + (size_t)g * FIN * 64) : W1o;
    Wt1[i] = f2bf(W[k * 64 + n]);
  } else if (i < n1 + n2) {
    const int j = i - n1;
    const int g = j / (64 * FH), rem = j % (64 * FH);
    const int n = rem / FH, k = rem % FH;
    const float* W = (g < NR) ? (W2r + (size_t)g * FH * 64) : W2o;
    Wt2[j] = f2bf(W[k * 64 + n]);
  }
}

// ---------------- MFMA GEMM body: A in regs, SINGLE-buffer B, swapped C -----
// mfma(b, a): D = (a*b)^T -> lane&15 = node, (lane>>4)*4+reg = feature.
// xw output REL-MAJOR: xw[g*NN*64 + node*64 + feat]. breg prefetch covers the
// global->reg latency; Bs refilled between two barriers per group.
template <int K, bool A_FP32, bool ROOT_BF16>
__device__ void gemm_body(char* smem, int bx,
                          const void* __restrict__ Av,
                          const unsigned short* __restrict__ Wt,
                          const float* __restrict__ bias,
                          unsigned short* __restrict__ xw,
                          void* __restrict__ root_out) {
  constexpr int KP  = K + 8;
  constexpr int NCH = 64 * (K / 8) / 256;
  constexpr int NKC = K / 32;
  unsigned short* Bs = (unsigned short*)smem;    // single buffer: 64*KP shorts
  const int n0  = bx * 64;
  const int tid = threadIdx.x;
  const int wave = tid >> 6, lane = tid & 63;
  const int i16 = lane & 15, quad = lane >> 4;
  const int node = n0 + wave * 16 + i16;

  bf16x8 afrag[NKC];
  if constexpr (A_FP32) {
    const float* A = (const float*)Av;
#pragma unroll
    for (int kc = 0; kc < NKC; ++kc) {
      bf16x8 v = {};
      if (node < NN) {
        const float* p = A + (size_t)node * K + kc * 32 + quad * 8;
        const float4 f0 = *(const float4*)p;
        const float4 f1 = *(const float4*)(p + 4);
        v[0] = f2bf(f0.x); v[1] = f2bf(f0.y); v[2] = f2bf(f0.z); v[3] = f2bf(f0.w);
        v[4] = f2bf(f1.x); v[5] = f2bf(f1.y); v[6] = f2bf(f1.z); v[7] = f2bf(f1.w);
      }
      afrag[kc] = v;
    }
  } else {
    const unsigned short* A = (const unsigned short*)Av;
#pragma unroll
    for (int kc = 0; kc < NKC; ++kc) {
      bf16x8 v = {};
      if (node < NN) v = *(const bf16x8*)(A + (size_t)node * K + kc * 32 + quad * 8);
      afrag[kc] = v;
    }
  }

  // stage B group 0
  for (int c = 0; c < NCH; ++c) {
    const int idx = tid + c * 256;
    const int row = idx / (K / 8), kp = (idx % (K / 8)) * 8;
    *(bf16x8*)(Bs + row * KP + kp) = *(const bf16x8*)(Wt + idx * 8);
  }
  __syncthreads();

  for (int g = 0; g <= NR; ++g) {
    bf16x8 breg[NCH];
    if (g < NR) {
      const unsigned short* Wn = Wt + (size_t)(g + 1) * 64 * K;
#pragma unroll
      for (int c = 0; c < NCH; ++c) breg[c] = *(const bf16x8*)(Wn + (tid + c * 256) * 8);
    }

    f32x4 acc[4] = {};
#pragma unroll
    for (int kc = 0; kc < NKC; ++kc) {
      const int k0 = kc * 32 + quad * 8;
      const bf16x8 a0 = afrag[kc];
      const bf16x8 b0 = *(const bf16x8*)(Bs + (i16)      * KP + k0);
      const bf16x8 b1 = *(const bf16x8*)(Bs + (i16 + 16) * KP + k0);
      const bf16x8 b2 = *(const bf16x8*)(Bs + (i16 + 32) * KP + k0);
      const bf16x8 b3 = *(const bf16x8*)(Bs + (i16 + 48) * KP + k0);
      acc[0] = __builtin_amdgcn_mfma_f32_16x16x32_bf16(b0, a0, acc[0], 0, 0, 0);
      acc[1] = __builtin_amdgcn_mfma_f32_16x16x32_bf16(b1, a0, acc[1], 0, 0, 0);
      acc[2] = __builtin_amdgcn_mfma_f32_16x16x32_bf16(b2, a0, acc[2], 0, 0, 0);
      acc[3] = __builtin_amdgcn_mfma_f32_16x16x32_bf16(b3, a0, acc[3], 0, 0, 0);
    }

    if (g < NR) {
      if (node < NN) {
        unsigned short* p = xw + (size_t)g * (NN * 64) + (size_t)node * 64 + quad * 4;
#pragma unroll
        for (int ct = 0; ct < 4; ++ct) {
          bf16x4 ov;
          ov[0] = (short)f2bf(acc[ct][0]); ov[1] = (short)f2bf(acc[ct][1]);
          ov[2] = (short)f2bf(acc[ct][2]); ov[3] = (short)f2bf(acc[ct][3]);
          *(bf16x4*)(p + ct * 16) = ov;
        }
      }
      __syncthreads();   // all waves done reading Bs
#pragma unroll
      for (int c = 0; c < NCH; ++c) {
        const int idx = tid + c * 256;
        const int row = idx / (K / 8), kp = (idx % (K / 8)) * 8;
        *(bf16x8*)(Bs + row * KP + kp) = breg[c];
      }
      __syncthreads();   // Bs refilled with group g+1
    } else if (node < NN) {
#pragma unroll
      for (int ct = 0; ct < 4; ++ct) {
        const float4 bv = *(const float4*)(bias + ct * 16 + quad * 4);
        const float o0 = acc[ct][0] + bv.x, o1 = acc[ct][1] + bv.y;
        const float o2 = acc[ct][2] + bv.z, o3 = acc[ct][3] + bv.w;
        if constexpr (ROOT_BF16) {
          unsigned short* p = (unsigned short*)root_out + (size_t)node * 64 + ct * 16 + quad * 4;
          bf16x4 ov;
          ov[0] = (short)f2bf(o0); ov[1] = (short)f2bf(o1);
          ov[2] = (short)f2bf(o2); ov[3] = (short)f2bf(o3);
          *(bf16x4*)p = ov;
        } else {
          float* p = (float*)root_out + (size_t)node * 64 + ct * 16 + quad * 4;
          *(float4*)p = make_float4(o0, o1, o2, o3);
        }
      }
    }
  }
}

// ---------------- fused dispatch: append (odd blocks) || gemm1 (even) -------
__global__ void __launch_bounds__(256) fused_append_gemm1(
    const int* __restrict__ src, const int* __restrict__ dst,
    const int* __restrict__ et, int* __restrict__ bcur,
    unsigned* __restrict__ brecs,
    const float* __restrict__ A, const unsigned short* __restrict__ Wt,
    const float* __restrict__ bias, unsigned short* __restrict__ xw,
    unsigned short* __restrict__ hroot) {
  extern __shared__ char smem[];
  const int bx = (int)blockIdx.x;
  if (bx & 1)
    append_body(smem, bx >> 1, src, dst, et, bcur, brecs);
  else
    gemm_body<FIN, true, true>(smem, bx >> 1, A, Wt, bias, xw, hroot);
}

__global__ void __launch_bounds__(256) gemm_l2(
    const unsigned short* __restrict__ A, const unsigned short* __restrict__ Wt,
    const float* __restrict__ bias, unsigned short* __restrict__ xw,
    float* __restrict__ out) {
  extern __shared__ char smem[];
  gemm_body<FH, false, false>(smem, (int)blockIdx.x, A, Wt, bias, xw, out);
}

// ---------------- aggregation: one wave/dst, 8 gathers in flight ------------
// lane = e(3b) | l8(3b). Record: cnt<<25 | addr(25b), addr = (r*NN+sv)*64.
template <bool RELU_BF16>
__global__ void __launch_bounds__(256) agg_csr(
    const int* __restrict__ row_start, const int* __restrict__ deg,
    const unsigned* __restrict__ recs, const unsigned short* __restrict__ xw,
    const void* __restrict__ rootv,
    float* __restrict__ out_f32, unsigned short* __restrict__ out_b16) {
  const int gid  = blockIdx.x * blockDim.x + threadIdx.x;
  const int lane = gid & 63;
  const int d    = gid >> 6;
  if (d >= NN) return;
  const int e  = lane >> 3;
  const int l8 = lane & 7;
  const int base = row_start[d];
  const int n    = deg[d];
  const unsigned* po = recs + base;
  const unsigned short* xp = xw + l8 * 8;
  float a[8] = {};

  int i0 = 0;
  for (; i0 + 32 < n; i0 += 64) {
    unsigned rr[8];
#pragma unroll
    for (int sl = 0; sl < 8; ++sl) {
      const int i = i0 + e + 8 * sl;
      rr[sl] = (i < n) ? po[i] : 0u;
    }
    bf16x8 vv[8];
#pragma unroll
    for (int sl = 0; sl < 8; ++sl)
      vv[sl] = *(const bf16x8*)(xp + (rr[sl] & 0x01FFFFFFu));
#pragma unroll
    for (int sl = 0; sl < 8; ++sl) {
      float w = __builtin_amdgcn_rcpf((float)(rr[sl] >> 25));
      if (i0 + e + 8 * sl >= n) w = 0.f;
#pragma unroll
      for (int q = 0; q < 8; ++q) a[q] += bf2f((unsigned short)vv[sl][q]) * w;
    }
  }
  if (i0 < n) {
    unsigned rr[4];
#pragma unroll
    for (int sl = 0; sl < 4; ++sl) {
      const int i = i0 + e + 8 * sl;
      rr[sl] = (i < n) ? po[i] : 0u;
    }
    bf16x8 vv[4];
#pragma unroll
    for (int sl = 0; sl < 4; ++sl)
      vv[sl] = *(const bf16x8*)(xp + (rr[sl] & 0x01FFFFFFu));
#pragma unroll
    for (int sl = 0; sl < 4; ++sl) {
      float w = __builtin_amdgcn_rcpf((float)(rr[sl] >> 25));
      if (i0 + e + 8 * sl >= n) w = 0.f;
#pragma unroll
      for (int q = 0; q < 8; ++q) a[q] += bf2f((unsigned short)vv[sl][q]) * w;
    }
  }

#pragma unroll
  for (int q = 0; q < 8; ++q) {
    a[q] += __shfl_xor(a[q], 8, 64);
    a[q] += __shfl_xor(a[q], 16, 64);
    a[q] += __shfl_xor(a[q], 32, 64);
  }

  if (e == 0) {
    float r[8];
    if constexpr (RELU_BF16) {
      const bf16x8 rv = *(const bf16x8*)((const unsigned short*)rootv + (size_t)d * 64 + l8 * 8);
#pragma unroll
      for (int q = 0; q < 8; ++q) r[q] = bf2f((unsigned short)rv[q]);
    } else {
      const float4 r0 = *(const float4*)((const float*)rootv + (size_t)d * 64 + l8 * 8);
      const float4 r1 = *(const float4*)((const float*)rootv + (size_t)d * 64 + l8 * 8 + 4);
      r[0] = r0.x; r[1] = r0.y; r[2] = r0.z; r[3] = r0.w;
      r[4] = r1.x; r[5] = r1.y; r[6] = r1.z; r[7] = r1.w;
    }
    float o[8];
#pragma unroll
    for (int q = 0; q < 8; ++q) o[q] = r[q] + a[q];
    if (RELU_BF16) {
      bf16x8 ov;
#pragma unroll
      for (int q = 0; q < 8; ++q) ov[q] = (short)f2bf(fmaxf(o[q], 0.f));
      *(bf16x8*)(out_b16 + (size_t)d * 64 + l8 * 8) = ov;
    } else {
      *(float4*)(out_f32 + (size_t)d * 64 + l8 * 8)     = make_float4(o[0], o[1], o[2], o[3]);
      *(float4*)(out_f32 + (size_t)d * 64 + l8 * 8 + 4) = make_float4(o[4], o[5], o[6], o[7]);
    }
  }
}

extern "C" void kernel_launch(void* const* d_in, const int* in_sizes, int n_in,
                              void* d_out, int out_size, void* d_ws, size_t ws_size,
                              hipStream_t stream) {
  const float* x   = (const float*)d_in[0];
  const int*   ei  = (const int*)d_in[1];
  const int*   et  = (const int*)d_in[2];
  const float* W1r = (const float*)d_in[3];
  const float* W1o = (const float*)d_in[4];
  const float* b1  = (const float*)d_in[5];
  const float* W2r = (const float*)d_in[6];
  const float* W2o = (const float*)d_in[7];
  const float* b2  = (const float*)d_in[8];
  float* out = (float*)d_out;

  const int* src = ei;
  const int* dst = ei + NE;

  char* ws = (char*)d_ws;
  size_t off = 0;
  auto alloc = [&](size_t bytes) {
    void* p = ws + off; off += (bytes + 255) & ~(size_t)255; return p;
  };
  int*   bcur      = (int*)alloc((size_t)NB * 4);
  int*   row_start = (int*)alloc((size_t)NN * 4);
  int*   deg       = (int*)alloc((size_t)NN * 4);
  unsigned* brecs  = (unsigned*)alloc((size_t)NB * CAP * 4);                //  9.6 MB
  unsigned* offs   = (unsigned*)alloc((size_t)NB * CAP * 4);                //  9.6 MB
  unsigned short* xw    = (unsigned short*)alloc((size_t)NN * NR * 64 * 2); // 51.2 MB (both layers)
  unsigned short* hb    = (unsigned short*)alloc((size_t)NN * FH * 2);      //  6.4 MB
  unsigned short* hroot = (unsigned short*)alloc((size_t)NN * 64 * 2);      //  6.4 MB
  float*          root2 = (float*)alloc((size_t)NN * 64 * 4);               // 12.8 MB
  unsigned short* Wt1   = (unsigned short*)alloc((size_t)(NR + 1) * 64 * FIN * 2);
  unsigned short* Wt2   = (unsigned short*)alloc((size_t)(NR + 1) * 64 * FH * 2);

  const int nprep = (NR + 1) * 64 * (FIN + FH);
  prep<<<(nprep + 255) / 256, 256, 0, stream>>>(W1r, W1o, W2r, W2o, Wt1, Wt2, bcur);

  const int gemm_blocks = (NN + 63) / 64;              // 782
  const int agg_blocks  = (NN * 64 + 255) / 256;       // 12500
  constexpr int SM1 = APPLDS;                          // 22656 (>= gemm 17408)
  constexpr int SM2 = 64 * (FH + 8) * 2;               // 9216

  // Layer 1 transform || CSR append (odd/even roles), then finalize.
  fused_append_gemm1<<<NAPP + gemm_blocks, 256, SM1, stream>>>(
      src, dst, et, bcur, brecs, x, Wt1, b1, xw, hroot);
  bucket_finalize<<<NB, 256, 0, stream>>>(bcur, brecs, row_start, deg, offs);

  // Layer 1 aggregate, Layer 2 transform + aggregate.
  agg_csr<true><<<agg_blocks, 256, 0, stream>>>(row_start, deg, offs, xw, hroot, nullptr, hb);
  gemm_l2<<<gemm_blocks, 256, SM2, stream>>>(hb, Wt2, b2, xw, root2);
  agg_csr<false><<<agg_blocks, 256, 0, stream>>>(row_start, deg, offs, xw, root2, out, nullptr);
}

// Round 8
// 244.106 us; speedup vs baseline: 1.0320x; 1.0320x over previous
//
#include <hip/hip_runtime.h>

// RGCN: N=50000, E=1.6M, R=8, 128 -> 64 -> 64.
// R19 = R14 VERBATIM (239.4us, best measured) + ONE change: agg_csr runs
// 2 dsts per wave (32 lanes/dst = 4 edge-slots x 8 feat-chunks, 8 slots per
// 32-edge iter). For the common deg~32 row this doubles in-flight gathers
// per lane (4 -> 8) and drops one shfl stage from the reduction.
// (Resubmission: previous round failed with a container infra error, no
// kernel evidence; source unchanged.)

constexpr int NN  = 50000;
constexpr int NE  = 1600000;
constexpr int NR  = 8;
constexpr int FIN = 128;
constexpr int FH  = 64;

constexpr int BSH = 7;                       // 128 dst nodes per bucket
constexpr int BN  = 1 << BSH;
constexpr int NB  = (NN + BN - 1) >> BSH;    // 391
constexpr int CAP = 6144;                    // bucket capacity (load ~4092±64)
constexpr int CH  = 4096;                    // edges per append block
constexpr int NAPP = (NE + CH - 1) / CH;     // 391 append blocks
constexpr unsigned XWMAX = (unsigned)(NN - 1) * (NR * 64) + (NR - 1) * 64;

typedef __attribute__((ext_vector_type(8))) short bf16x8;
typedef __attribute__((ext_vector_type(4))) float f32x4;

__device__ __forceinline__ unsigned short f2bf(float f) {
  unsigned u = __float_as_uint(f);
  u = (u + 0x7fff + ((u >> 16) & 1)) >> 16;   // RNE
  return (unsigned short)u;
}
__device__ __forceinline__ float bf2f(unsigned short b) {
  return __uint_as_float(((unsigned)b) << 16);
}
__device__ __forceinline__ bool edge_ok(unsigned s, unsigned d, unsigned r) {
  return s < NN && d < NN && r < NR;
}

// ---------------- CSR build: append (device body, LDS via pointer) ----------
// LDS: stage[CH] (32768B) | h[NB] | gbase[NB] | sbase[NB] | scur[NB] | wtot[4]
__device__ void append_body(char* smem, int bx,
                            const int* __restrict__ src,
                            const int* __restrict__ dst,
                            const int* __restrict__ et,
                            int* __restrict__ bcur,
                            unsigned* __restrict__ brecs) {
  uint2* stage = (uint2*)smem;
  int* h     = (int*)(smem + (size_t)CH * 8);
  int* gbase = h + NB;
  int* sbase = gbase + NB;
  int* scur  = sbase + NB;
  int* wtot  = scur + NB;

  const int t  = threadIdx.x;
  const int c0 = bx * CH;
  const int m  = min(CH, NE - c0);

  for (int i = t; i < NB; i += 256) h[i] = 0;
  __syncthreads();

  for (int i = t; i < m; i += 256) {
    const unsigned s = (unsigned)src[c0 + i];
    const unsigned d = (unsigned)dst[c0 + i];
    const unsigned r = (unsigned)et[c0 + i];
    if (edge_ok(s, d, r)) atomicAdd(&h[d >> BSH], 1);
  }
  __syncthreads();

  const int v0 = (2 * t < NB) ? h[2 * t] : 0;
  const int v1 = (2 * t + 1 < NB) ? h[2 * t + 1] : 0;
  if (2 * t < NB     && v0) gbase[2 * t]     = atomicAdd(&bcur[2 * t], v0);
  if (2 * t + 1 < NB && v1) gbase[2 * t + 1] = atomicAdd(&bcur[2 * t + 1], v1);
  const int s = v0 + v1;
  int incl = s;
#pragma unroll
  for (int o = 1; o < 64; o <<= 1) {
    int u = __shfl_up(incl, o, 64);
    if ((t & 63) >= o) incl += u;
  }
  if ((t & 63) == 63) wtot[t >> 6] = incl;
  __syncthreads();
  int wo = 0;
  for (int w = 0; w < (t >> 6); ++w) wo += wtot[w];
  const int e = wo + incl - s;
  if (2 * t < NB)     { sbase[2 * t] = e;          scur[2 * t] = e; }
  if (2 * t + 1 < NB) { sbase[2 * t + 1] = e + v0; scur[2 * t + 1] = e + v0; }
  __syncthreads();

  for (int i = t; i < m; i += 256) {
    const unsigned sv = (unsigned)src[c0 + i];
    const unsigned d  = (unsigned)dst[c0 + i];
    const unsigned r  = (unsigned)et[c0 + i];
    if (edge_ok(sv, d, r)) {
      const int p = atomicAdd(&scur[d >> BSH], 1);
      if (p < CH) stage[p] = make_uint2((sv << 10) | (((unsigned)d & (BN - 1)) << 3) | r, d);
    }
  }
  __syncthreads();

  const int M = min(sbase[NB - 1] + h[NB - 1], CH);
  for (int j = t; j < M; j += 256) {
    const uint2 rec = stage[j];
    const int b = (int)(rec.y >> BSH);
    const int idx = min(gbase[b] + (j - sbase[b]), NB * CAP - 1);
    brecs[idx] = rec.x;
  }
}

// ---------------- CSR build: finalize ----------------
// Records: cnt<<25 | sv<<9 | r<<6. Weight 1/cnt via v_rcp in agg.
__global__ void __launch_bounds__(256) bucket_finalize(
    const int* __restrict__ bcur, const unsigned* __restrict__ brecs,
    int* __restrict__ row_start, int* __restrict__ deg,
    unsigned* __restrict__ recs) {
  const int b    = blockIdx.x;
  const int base = b * CAP;
  const int m    = min(bcur[b] - base, CAP);
  const int d0   = b << BSH;
  __shared__ int cnt[BN * NR];
  __shared__ int curs[BN * NR];
  __shared__ int wtot[4];
  const int t = threadIdx.x;

  for (int i = t; i < BN * NR; i += 256) cnt[i] = 0;
  __syncthreads();
  for (int i = t; i < m; i += 256) {
    const unsigned rec = brecs[base + i];
    const int dl = (int)((rec >> 3) & (BN - 1));
    const int r  = (int)(rec & 7);
    atomicAdd(&cnt[dl * NR + r], 1);
  }
  __syncthreads();

  const int c0 = cnt[t * 4], c1 = cnt[t * 4 + 1], c2 = cnt[t * 4 + 2], c3 = cnt[t * 4 + 3];
  const int s = c0 + c1 + c2 + c3;
  int incl = s;
#pragma unroll
  for (int o = 1; o < 64; o <<= 1) {
    int u = __shfl_up(incl, o, 64);
    if ((t & 63) >= o) incl += u;
  }
  if ((t & 63) == 63) wtot[t >> 6] = incl;
  __syncthreads();
  int wo = 0;
  for (int w = 0; w < (t >> 6); ++w) wo += wtot[w];
  const int e = wo + incl - s;
  curs[t * 4]     = e;
  curs[t * 4 + 1] = e + c0;
  curs[t * 4 + 2] = e + c0 + c1;
  curs[t * 4 + 3] = e + c0 + c1 + c2;
  __syncthreads();

  if (t < BN) {
    const int d = d0 + t;
    if (d < NN) {
      const int start = curs[t * NR];
      const int end   = (t == BN - 1) ? m : curs[(t + 1) * NR];
      row_start[d] = base + start;
      deg[d]       = end - start;
    }
  }
  __syncthreads();

  for (int i = t; i < m; i += 256) {
    const unsigned rec = brecs[base + i];
    const int dl = (int)((rec >> 3) & (BN - 1));
    const int r  = (int)(rec & 7);
    const unsigned sv = rec >> 10;
    const int p  = atomicAdd(&curs[dl * NR + r], 1);
    const unsigned cn = (unsigned)min(cnt[dl * NR + r], 127);
    recs[base + min(p, CAP - 1)] = (cn << 25) | (sv << 9) | ((unsigned)r << 6);
  }
}

// ---------------- prep: bcur init + weights -> bf16 transposed ----------------
__global__ void prep(const float* __restrict__ W1r, const float* __restrict__ W1o,
                     const float* __restrict__ W2r, const float* __restrict__ W2o,
                     unsigned short* __restrict__ Wt1,
                     unsigned short* __restrict__ Wt2,
                     int* __restrict__ bcur) {
  const int i  = blockIdx.x * blockDim.x + threadIdx.x;
  if (i < NB) bcur[i] = i * CAP;
  const int n1 = (NR + 1) * 64 * FIN;
  const int n2 = (NR + 1) * 64 * FH;
  if (i < n1) {
    const int g = i / (64 * FIN), rem = i % (64 * FIN);
    const int n = rem / FIN, k = rem % FIN;
    const float* W = (g < NR) ? (W1r + (size_t)g * FIN * 64) : W1o;
    Wt1[i] = f2bf(W[k * 64 + n]);
  } else if (i < n1 + n2) {
    const int j = i - n1;
    const int g = j / (64 * FH), rem = j % (64 * FH);
    const int n = rem / FH, k = rem % FH;
    const float* W = (g < NR) ? (W2r + (size_t)g * FH * 64) : W2o;
    Wt2[j] = f2bf(W[k * 64 + n]);
  }
}

// ---------------- MFMA GEMM body: A in registers, B-dbuf in LDS ------------
template <int K, bool A_FP32>
__device__ void gemm_body(char* smem, int bx,
                          const void* __restrict__ Av,
                          const unsigned short* __restrict__ Wt,
                          const float* __restrict__ bias,
                          unsigned short* __restrict__ xw,
                          float* __restrict__ root_out) {
  constexpr int KP  = K + 8;
  constexpr int NCH = 64 * (K / 8) / 256;
  constexpr int NKC = K / 32;
  unsigned short* Bs0 = (unsigned short*)smem;   // dbuf halves: 2 x 64*KP
  const int n0  = bx * 64;
  const int tid = threadIdx.x;
  const int wave = tid >> 6, lane = tid & 63;
  const int i16 = lane & 15, quad = lane >> 4;
  const int r0 = wave * 16 + i16;
  const int arow = n0 + r0;

  bf16x8 afrag[NKC];
  if constexpr (A_FP32) {
    const float* A = (const float*)Av;
#pragma unroll
    for (int kc = 0; kc < NKC; ++kc) {
      bf16x8 v = {};
      if (arow < NN) {
        const float* p = A + (size_t)arow * K + kc * 32 + quad * 8;
        const float4 f0 = *(const float4*)p;
        const float4 f1 = *(const float4*)(p + 4);
        v[0] = f2bf(f0.x); v[1] = f2bf(f0.y); v[2] = f2bf(f0.z); v[3] = f2bf(f0.w);
        v[4] = f2bf(f1.x); v[5] = f2bf(f1.y); v[6] = f2bf(f1.z); v[7] = f2bf(f1.w);
      }
      afrag[kc] = v;
    }
  } else {
    const unsigned short* A = (const unsigned short*)Av;
#pragma unroll
    for (int kc = 0; kc < NKC; ++kc) {
      bf16x8 v = {};
      if (arow < NN) v = *(const bf16x8*)(A + (size_t)arow * K + kc * 32 + quad * 8);
      afrag[kc] = v;
    }
  }

  for (int c = 0; c < NCH; ++c) {
    const int idx = tid + c * 256;
    const int row = idx / (K / 8), kp = (idx % (K / 8)) * 8;
    *(bf16x8*)(Bs0 + row * KP + kp) = *(const bf16x8*)(Wt + idx * 8);
  }
  __syncthreads();

  for (int g = 0; g <= NR; ++g) {
    const int buf = g & 1;
    unsigned short* Bc = Bs0 + buf * 64 * KP;
    unsigned short* Bn = Bs0 + (buf ^ 1) * 64 * KP;
    bf16x8 breg[NCH];
    if (g < NR) {
      const unsigned short* Wn = Wt + (size_t)(g + 1) * 64 * K;
#pragma unroll
      for (int c = 0; c < NCH; ++c) breg[c] = *(const bf16x8*)(Wn + (tid + c * 256) * 8);
    }

    f32x4 acc[4] = {};
#pragma unroll
    for (int kc = 0; kc < NKC; ++kc) {
      const int k0 = kc * 32 + quad * 8;
      const bf16x8 a0 = afrag[kc];
      const bf16x8 b0 = *(const bf16x8*)(Bc + (i16)      * KP + k0);
      const bf16x8 b1 = *(const bf16x8*)(Bc + (i16 + 16) * KP + k0);
      const bf16x8 b2 = *(const bf16x8*)(Bc + (i16 + 32) * KP + k0);
      const bf16x8 b3 = *(const bf16x8*)(Bc + (i16 + 48) * KP + k0);
      acc[0] = __builtin_amdgcn_mfma_f32_16x16x32_bf16(a0, b0, acc[0], 0, 0, 0);
      acc[1] = __builtin_amdgcn_mfma_f32_16x16x32_bf16(a0, b1, acc[1], 0, 0, 0);
      acc[2] = __builtin_amdgcn_mfma_f32_16x16x32_bf16(a0, b2, acc[2], 0, 0, 0);
      acc[3] = __builtin_amdgcn_mfma_f32_16x16x32_bf16(a0, b3, acc[3], 0, 0, 0);
    }

    if (g < NR) {
#pragma unroll
      for (int c = 0; c < NCH; ++c) {
        const int idx = tid + c * 256;
        const int row = idx / (K / 8), kp = (idx % (K / 8)) * 8;
        *(bf16x8*)(Bn + row * KP + kp) = breg[c];
      }
#pragma unroll
      for (int reg = 0; reg < 4; ++reg) {
        const int n = n0 + wave * 16 + quad * 4 + reg;
        if (n >= NN) continue;
        unsigned short* p = xw + (size_t)n * (NR * 64) + g * 64 + i16;
#pragma unroll
        for (int ct = 0; ct < 4; ++ct) p[ct * 16] = f2bf(acc[ct][reg]);
      }
    } else {
      float bv[4];
#pragma unroll
      for (int ct = 0; ct < 4; ++ct) bv[ct] = bias[ct * 16 + i16];
#pragma unroll
      for (int reg = 0; reg < 4; ++reg) {
        const int n = n0 + wave * 16 + quad * 4 + reg;
        if (n >= NN) continue;
        float* p = root_out + (size_t)n * 64 + i16;
#pragma unroll
        for (int ct = 0; ct < 4; ++ct) p[ct * 16] = acc[ct][reg] + bv[ct];
      }
    }
    __syncthreads();
  }
}

// ---------------- fused dispatch: append interleaved with gemm1 -------------
// blockIdx%3==2 -> append (391 of them, ids bx/3); others -> gemm
// (id = bx - (appends before bx) = bx - (bx+1)/3).
__global__ void __launch_bounds__(256) fused_append_gemm1(
    const int* __restrict__ src, const int* __restrict__ dst,
    const int* __restrict__ et, int* __restrict__ bcur,
    unsigned* __restrict__ brecs,
    const float* __restrict__ A, const unsigned short* __restrict__ Wt,
    const float* __restrict__ bias, unsigned short* __restrict__ xw,
    float* __restrict__ root_out) {
  extern __shared__ char smem[];
  const int bx = (int)blockIdx.x;
  if (bx % 3 == 2 && bx / 3 < NAPP)
    append_body(smem, bx / 3, src, dst, et, bcur, brecs);
  else
    gemm_body<FIN, true>(smem, bx - (bx + 1) / 3, A, Wt, bias, xw, root_out);
}

__global__ void __launch_bounds__(256) gemm_l2(
    const unsigned short* __restrict__ A, const unsigned short* __restrict__ Wt,
    const float* __restrict__ bias, unsigned short* __restrict__ xw,
    float* __restrict__ out) {
  extern __shared__ char smem[];
  gemm_body<FH, false>(smem, (int)blockIdx.x, A, Wt, bias, xw, out);
}

// ---------------- aggregation: 2 dsts per wave, 8 gathers in flight ---------
// lane = half(1b) | e(2b) | l8(3b): half selects dst, e = edge slot (4),
// l8 = feature chunk (8). Per 32-edge iteration each lane issues 8 gathers
// (slots i0 + e + 4*sl, sl=0..7). Record: cnt<<25 | sv<<9 | r<<6.
template <bool RELU_BF16>
__global__ void __launch_bounds__(256) agg_csr(
    const int* __restrict__ row_start, const int* __restrict__ deg,
    const unsigned* __restrict__ recs, const unsigned short* __restrict__ xw,
    const float* __restrict__ root,
    float* __restrict__ out_f32, unsigned short* __restrict__ out_b16) {
  const int gid  = blockIdx.x * blockDim.x + threadIdx.x;
  const int lane = gid & 63;
  const int wv   = gid >> 6;                  // wave id: owns dsts 2wv, 2wv+1
  const int half = lane >> 5;
  const int sub  = lane & 31;
  const int e  = sub >> 3;                    // 0..3
  const int l8 = sub & 7;
  const int d  = wv * 2 + half;
  if (d >= NN) return;
  const int base = row_start[d];
  const int n    = deg[d];
  const unsigned* po = recs + base;
  const unsigned short* xp = xw + l8 * 8;
  float a[8] = {};

  for (int i0 = 0; i0 < n; i0 += 32) {
    unsigned rr[8];
#pragma unroll
    for (int sl = 0; sl < 8; ++sl) {
      const int i = i0 + e + 4 * sl;
      rr[sl] = (i < n) ? po[i] : 0u;
    }
    bf16x8 vv[8];
#pragma unroll
    for (int sl = 0; sl < 8; ++sl) {
      const unsigned u = min(rr[sl] & 0x01FFFFFFu, XWMAX);
      vv[sl] = *(const bf16x8*)(xp + u);
    }
#pragma unroll
    for (int sl = 0; sl < 8; ++sl) {
      float w = __builtin_amdgcn_rcpf((float)(rr[sl] >> 25));
      if (i0 + e + 4 * sl >= n) w = 0.f;
#pragma unroll
      for (int q = 0; q < 8; ++q) a[q] += bf2f((unsigned short)vv[sl][q]) * w;
    }
  }

  // reduce across the 4 e-groups within each 32-lane half (xor 8, 16 stay
  // inside the half; the two dst halves never mix).
#pragma unroll
  for (int q = 0; q < 8; ++q) {
    a[q] += __shfl_xor(a[q], 8, 64);
    a[q] += __shfl_xor(a[q], 16, 64);
  }

  if (e == 0) {
    const float4 r0 = *(const float4*)(root + (size_t)d * 64 + l8 * 8);
    const float4 r1 = *(const float4*)(root + (size_t)d * 64 + l8 * 8 + 4);
    const float o[8] = {r0.x + a[0], r0.y + a[1], r0.z + a[2], r0.w + a[3],
                        r1.x + a[4], r1.y + a[5], r1.z + a[6], r1.w + a[7]};
    if (RELU_BF16) {
      bf16x8 ov;
#pragma unroll
      for (int q = 0; q < 8; ++q) ov[q] = (short)f2bf(fmaxf(o[q], 0.f));
      *(bf16x8*)(out_b16 + (size_t)d * 64 + l8 * 8) = ov;
    } else {
      *(float4*)(out_f32 + (size_t)d * 64 + l8 * 8)     = make_float4(o[0], o[1], o[2], o[3]);
      *(float4*)(out_f32 + (size_t)d * 64 + l8 * 8 + 4) = make_float4(o[4], o[5], o[6], o[7]);
    }
  }
}

extern "C" void kernel_launch(void* const* d_in, const int* in_sizes, int n_in,
                              void* d_out, int out_size, void* d_ws, size_t ws_size,
                              hipStream_t stream) {
  const float* x   = (const float*)d_in[0];
  const int*   ei  = (const int*)d_in[1];
  const int*   et  = (const int*)d_in[2];
  const float* W1r = (const float*)d_in[3];
  const float* W1o = (const float*)d_in[4];
  const float* b1  = (const float*)d_in[5];
  const float* W2r = (const float*)d_in[6];
  const float* W2o = (const float*)d_in[7];
  const float* b2  = (const float*)d_in[8];
  float* out = (float*)d_out;

  const int* src = ei;
  const int* dst = ei + NE;

  char* ws = (char*)d_ws;
  size_t off = 0;
  auto alloc = [&](size_t bytes) {
    void* p = ws + off; off += (bytes + 255) & ~(size_t)255; return p;
  };
  int*   bcur      = (int*)alloc((size_t)NB * 4);
  int*   row_start = (int*)alloc((size_t)NN * 4);
  int*   deg       = (int*)alloc((size_t)NN * 4);
  unsigned* brecs  = (unsigned*)alloc((size_t)NB * CAP * 4);                //  9.6 MB
  unsigned* offs   = (unsigned*)alloc((size_t)NB * CAP * 4);                //  9.6 MB
  unsigned short* xw    = (unsigned short*)alloc((size_t)NN * NR * 64 * 2); // 51.2 MB
  unsigned short* hb    = (unsigned short*)alloc((size_t)NN * FH * 2);      //  6.4 MB
  float*          hroot = (float*)alloc((size_t)NN * 64 * 4);               // 12.8 MB
  unsigned short* Wt1   = (unsigned short*)alloc((size_t)(NR + 1) * 64 * FIN * 2);
  unsigned short* Wt2   = (unsigned short*)alloc((size_t)(NR + 1) * 64 * FH * 2);

  const int nprep = (NR + 1) * 64 * (FIN + FH);
  prep<<<(nprep + 255) / 256, 256, 0, stream>>>(W1r, W1o, W2r, W2o, Wt1, Wt2, bcur);

  const int gemm_blocks = (NN + 63) / 64;                  // 782
  const int agg_blocks  = ((NN + 1) / 2 + 3) / 4;          // 6250 (2 dst/wave)
  constexpr int SM1 = CH * 8 + 4 * NB * 4 + 16;            // 39040 (>= gemm 34816)
  constexpr int SM2 = 2 * 64 * (FH + 8) * 2;               // 18432

  // Layer 1 transform || CSR append (interleaved roles), then finalize.
  fused_append_gemm1<<<NAPP + gemm_blocks, 256, SM1, stream>>>(
      src, dst, et, bcur, brecs, x, Wt1, b1, xw, hroot);
  bucket_finalize<<<NB, 256, 0, stream>>>(bcur, brecs, row_start, deg, offs);

  // Layer 1 aggregate, Layer 2 transform + aggregate.
  agg_csr<true><<<agg_blocks, 256, 0, stream>>>(row_start, deg, offs, xw, hroot, nullptr, hb);
  gemm_l2<<<gemm_blocks, 256, SM2, stream>>>(hb, Wt2, b2, xw, out);
  agg_csr<false><<<agg_blocks, 256, 0, stream>>>(row_start, deg, offs, xw, out, out, nullptr);
}

// Round 9
// 244.017 us; speedup vs baseline: 1.0324x; 1.0004x over previous
//
#include <hip/hip_runtime.h>

// RGCN: N=50000, E=1.6M, R=8, 128 -> 64 -> 64.
// R20 = R14 VERBATIM (239.4us best) + ONE logical change: gemm epilogue.
//   - MFMA operands swapped (mfma(b,a) => D^T): lane&15 = node,
//     (lane>>4)*4+reg = feature. xw stores become 4x8B vector stores per
//     group (was 16x2B scalar); root write vectorized too.
//   - hroot stored bf16 (write 12.8->6.4MB; agg1 root read halves).
// R19's 2-dst/wave agg REVERTED (measured neutral: MLP not agg's binding
// constraint). Everything else identical to R14.

constexpr int NN  = 50000;
constexpr int NE  = 1600000;
constexpr int NR  = 8;
constexpr int FIN = 128;
constexpr int FH  = 64;

constexpr int BSH = 7;                       // 128 dst nodes per bucket
constexpr int BN  = 1 << BSH;
constexpr int NB  = (NN + BN - 1) >> BSH;    // 391
constexpr int CAP = 6144;                    // bucket capacity (load ~4092±64)
constexpr int CH  = 4096;                    // edges per append block
constexpr int NAPP = (NE + CH - 1) / CH;     // 391 append blocks
constexpr unsigned XWMAX = (unsigned)(NN - 1) * (NR * 64) + (NR - 1) * 64;

typedef __attribute__((ext_vector_type(8))) short bf16x8;
typedef __attribute__((ext_vector_type(4))) short bf16x4;
typedef __attribute__((ext_vector_type(4))) float f32x4;

__device__ __forceinline__ unsigned short f2bf(float f) {
  unsigned u = __float_as_uint(f);
  u = (u + 0x7fff + ((u >> 16) & 1)) >> 16;   // RNE
  return (unsigned short)u;
}
__device__ __forceinline__ float bf2f(unsigned short b) {
  return __uint_as_float(((unsigned)b) << 16);
}
__device__ __forceinline__ bool edge_ok(unsigned s, unsigned d, unsigned r) {
  return s < NN && d < NN && r < NR;
}

// ---------------- CSR build: append (device body, LDS via pointer) ----------
// LDS: stage[CH] (32768B) | h[NB] | gbase[NB] | sbase[NB] | scur[NB] | wtot[4]
__device__ void append_body(char* smem, int bx,
                            const int* __restrict__ src,
                            const int* __restrict__ dst,
                            const int* __restrict__ et,
                            int* __restrict__ bcur,
                            unsigned* __restrict__ brecs) {
  uint2* stage = (uint2*)smem;
  int* h     = (int*)(smem + (size_t)CH * 8);
  int* gbase = h + NB;
  int* sbase = gbase + NB;
  int* scur  = sbase + NB;
  int* wtot  = scur + NB;

  const int t  = threadIdx.x;
  const int c0 = bx * CH;
  const int m  = min(CH, NE - c0);

  for (int i = t; i < NB; i += 256) h[i] = 0;
  __syncthreads();

  for (int i = t; i < m; i += 256) {
    const unsigned s = (unsigned)src[c0 + i];
    const unsigned d = (unsigned)dst[c0 + i];
    const unsigned r = (unsigned)et[c0 + i];
    if (edge_ok(s, d, r)) atomicAdd(&h[d >> BSH], 1);
  }
  __syncthreads();

  const int v0 = (2 * t < NB) ? h[2 * t] : 0;
  const int v1 = (2 * t + 1 < NB) ? h[2 * t + 1] : 0;
  if (2 * t < NB     && v0) gbase[2 * t]     = atomicAdd(&bcur[2 * t], v0);
  if (2 * t + 1 < NB && v1) gbase[2 * t + 1] = atomicAdd(&bcur[2 * t + 1], v1);
  const int s = v0 + v1;
  int incl = s;
#pragma unroll
  for (int o = 1; o < 64; o <<= 1) {
    int u = __shfl_up(incl, o, 64);
    if ((t & 63) >= o) incl += u;
  }
  if ((t & 63) == 63) wtot[t >> 6] = incl;
  __syncthreads();
  int wo = 0;
  for (int w = 0; w < (t >> 6); ++w) wo += wtot[w];
  const int e = wo + incl - s;
  if (2 * t < NB)     { sbase[2 * t] = e;          scur[2 * t] = e; }
  if (2 * t + 1 < NB) { sbase[2 * t + 1] = e + v0; scur[2 * t + 1] = e + v0; }
  __syncthreads();

  for (int i = t; i < m; i += 256) {
    const unsigned sv = (unsigned)src[c0 + i];
    const unsigned d  = (unsigned)dst[c0 + i];
    const unsigned r  = (unsigned)et[c0 + i];
    if (edge_ok(sv, d, r)) {
      const int p = atomicAdd(&scur[d >> BSH], 1);
      if (p < CH) stage[p] = make_uint2((sv << 10) | (((unsigned)d & (BN - 1)) << 3) | r, d);
    }
  }
  __syncthreads();

  const int M = min(sbase[NB - 1] + h[NB - 1], CH);
  for (int j = t; j < M; j += 256) {
    const uint2 rec = stage[j];
    const int b = (int)(rec.y >> BSH);
    const int idx = min(gbase[b] + (j - sbase[b]), NB * CAP - 1);
    brecs[idx] = rec.x;
  }
}

// ---------------- CSR build: finalize ----------------
// Records: cnt<<25 | sv<<9 | r<<6. Weight 1/cnt via v_rcp in agg.
__global__ void __launch_bounds__(256) bucket_finalize(
    const int* __restrict__ bcur, const unsigned* __restrict__ brecs,
    int* __restrict__ row_start, int* __restrict__ deg,
    unsigned* __restrict__ recs) {
  const int b    = blockIdx.x;
  const int base = b * CAP;
  const int m    = min(bcur[b] - base, CAP);
  const int d0   = b << BSH;
  __shared__ int cnt[BN * NR];
  __shared__ int curs[BN * NR];
  __shared__ int wtot[4];
  const int t = threadIdx.x;

  for (int i = t; i < BN * NR; i += 256) cnt[i] = 0;
  __syncthreads();
  for (int i = t; i < m; i += 256) {
    const unsigned rec = brecs[base + i];
    const int dl = (int)((rec >> 3) & (BN - 1));
    const int r  = (int)(rec & 7);
    atomicAdd(&cnt[dl * NR + r], 1);
  }
  __syncthreads();

  const int c0 = cnt[t * 4], c1 = cnt[t * 4 + 1], c2 = cnt[t * 4 + 2], c3 = cnt[t * 4 + 3];
  const int s = c0 + c1 + c2 + c3;
  int incl = s;
#pragma unroll
  for (int o = 1; o < 64; o <<= 1) {
    int u = __shfl_up(incl, o, 64);
    if ((t & 63) >= o) incl += u;
  }
  if ((t & 63) == 63) wtot[t >> 6] = incl;
  __syncthreads();
  int wo = 0;
  for (int w = 0; w < (t >> 6); ++w) wo += wtot[w];
  const int e = wo + incl - s;
  curs[t * 4]     = e;
  curs[t * 4 + 1] = e + c0;
  curs[t * 4 + 2] = e + c0 + c1;
  curs[t * 4 + 3] = e + c0 + c1 + c2;
  __syncthreads();

  if (t < BN) {
    const int d = d0 + t;
    if (d < NN) {
      const int start = curs[t * NR];
      const int end   = (t == BN - 1) ? m : curs[(t + 1) * NR];
      row_start[d] = base + start;
      deg[d]       = end - start;
    }
  }
  __syncthreads();

  for (int i = t; i < m; i += 256) {
    const unsigned rec = brecs[base + i];
    const int dl = (int)((rec >> 3) & (BN - 1));
    const int r  = (int)(rec & 7);
    const unsigned sv = rec >> 10;
    const int p  = atomicAdd(&curs[dl * NR + r], 1);
    const unsigned cn = (unsigned)min(cnt[dl * NR + r], 127);
    recs[base + min(p, CAP - 1)] = (cn << 25) | (sv << 9) | ((unsigned)r << 6);
  }
}

// ---------------- prep: bcur init + weights -> bf16 transposed ----------------
__global__ void prep(const float* __restrict__ W1r, const float* __restrict__ W1o,
                     const float* __restrict__ W2r, const float* __restrict__ W2o,
                     unsigned short* __restrict__ Wt1,
                     unsigned short* __restrict__ Wt2,
                     int* __restrict__ bcur) {
  const int i  = blockIdx.x * blockDim.x + threadIdx.x;
  if (i < NB) bcur[i] = i * CAP;
  const int n1 = (NR + 1) * 64 * FIN;
  const int n2 = (NR + 1) * 64 * FH;
  if (i < n1) {
    const int g = i / (64 * FIN), rem = i % (64 * FIN);
    const int n = rem / FIN, k = rem % FIN;
    const float* W = (g < NR) ? (W1r + (size_t)g * FIN * 64) : W1o;
    Wt1[i] = f2bf(W[k * 64 + n]);
  } else if (i < n1 + n2) {
    const int j = i - n1;
    const int g = j / (64 * FH), rem = j % (64 * FH);
    const int n = rem / FH, k = rem % FH;
    const float* W = (g < NR) ? (W2r + (size_t)g * FH * 64) : W2o;
    Wt2[j] = f2bf(W[k * 64 + n]);
  }
}

// ---------------- MFMA GEMM body: A in regs, B-dbuf LDS, swapped C ----------
// mfma(b, a): D = (a*b)^T -> lane&15 = node (== this lane's A row), and
// (lane>>4)*4+reg = output feature. Epilogue: 4x 8B (bf16x4) or 16B (float4)
// vector stores per group. xw layout node-major [node][rel][64] (as R14).
template <int K, bool A_FP32, bool ROOT_BF16>
__device__ void gemm_body(char* smem, int bx,
                          const void* __restrict__ Av,
                          const unsigned short* __restrict__ Wt,
                          const float* __restrict__ bias,
                          unsigned short* __restrict__ xw,
                          void* __restrict__ root_out) {
  constexpr int KP  = K + 8;
  constexpr int NCH = 64 * (K / 8) / 256;
  constexpr int NKC = K / 32;
  unsigned short* Bs0 = (unsigned short*)smem;   // dbuf halves: 2 x 64*KP
  const int n0  = bx * 64;
  const int tid = threadIdx.x;
  const int wave = tid >> 6, lane = tid & 63;
  const int i16 = lane & 15, quad = lane >> 4;
  const int node = n0 + wave * 16 + i16;    // this lane's A row AND output node

  bf16x8 afrag[NKC];
  if constexpr (A_FP32) {
    const float* A = (const float*)Av;
#pragma unroll
    for (int kc = 0; kc < NKC; ++kc) {
      bf16x8 v = {};
      if (node < NN) {
        const float* p = A + (size_t)node * K + kc * 32 + quad * 8;
        const float4 f0 = *(const float4*)p;
        const float4 f1 = *(const float4*)(p + 4);
        v[0] = f2bf(f0.x); v[1] = f2bf(f0.y); v[2] = f2bf(f0.z); v[3] = f2bf(f0.w);
        v[4] = f2bf(f1.x); v[5] = f2bf(f1.y); v[6] = f2bf(f1.z); v[7] = f2bf(f1.w);
      }
      afrag[kc] = v;
    }
  } else {
    const unsigned short* A = (const unsigned short*)Av;
#pragma unroll
    for (int kc = 0; kc < NKC; ++kc) {
      bf16x8 v = {};
      if (node < NN) v = *(const bf16x8*)(A + (size_t)node * K + kc * 32 + quad * 8);
      afrag[kc] = v;
    }
  }

  for (int c = 0; c < NCH; ++c) {
    const int idx = tid + c * 256;
    const int row = idx / (K / 8), kp = (idx % (K / 8)) * 8;
    *(bf16x8*)(Bs0 + row * KP + kp) = *(const bf16x8*)(Wt + idx * 8);
  }
  __syncthreads();

  for (int g = 0; g <= NR; ++g) {
    const int buf = g & 1;
    unsigned short* Bc = Bs0 + buf * 64 * KP;
    unsigned short* Bn = Bs0 + (buf ^ 1) * 64 * KP;
    bf16x8 breg[NCH];
    if (g < NR) {
      const unsigned short* Wn = Wt + (size_t)(g + 1) * 64 * K;
#pragma unroll
      for (int c = 0; c < NCH; ++c) breg[c] = *(const bf16x8*)(Wn + (tid + c * 256) * 8);
    }

    f32x4 acc[4] = {};
#pragma unroll
    for (int kc = 0; kc < NKC; ++kc) {
      const int k0 = kc * 32 + quad * 8;
      const bf16x8 a0 = afrag[kc];
      const bf16x8 b0 = *(const bf16x8*)(Bc + (i16)      * KP + k0);
      const bf16x8 b1 = *(const bf16x8*)(Bc + (i16 + 16) * KP + k0);
      const bf16x8 b2 = *(const bf16x8*)(Bc + (i16 + 32) * KP + k0);
      const bf16x8 b3 = *(const bf16x8*)(Bc + (i16 + 48) * KP + k0);
      // swapped operands: D = (a*b)^T
      acc[0] = __builtin_amdgcn_mfma_f32_16x16x32_bf16(b0, a0, acc[0], 0, 0, 0);
      acc[1] = __builtin_amdgcn_mfma_f32_16x16x32_bf16(b1, a0, acc[1], 0, 0, 0);
      acc[2] = __builtin_amdgcn_mfma_f32_16x16x32_bf16(b2, a0, acc[2], 0, 0, 0);
      acc[3] = __builtin_amdgcn_mfma_f32_16x16x32_bf16(b3, a0, acc[3], 0, 0, 0);
    }

    if (g < NR) {
#pragma unroll
      for (int c = 0; c < NCH; ++c) {
        const int idx = tid + c * 256;
        const int row = idx / (K / 8), kp = (idx % (K / 8)) * 8;
        *(bf16x8*)(Bn + row * KP + kp) = breg[c];
      }
      if (node < NN) {
        unsigned short* p = xw + (size_t)node * (NR * 64) + g * 64 + quad * 4;
#pragma unroll
        for (int ct = 0; ct < 4; ++ct) {
          bf16x4 ov;
          ov[0] = (short)f2bf(acc[ct][0]); ov[1] = (short)f2bf(acc[ct][1]);
          ov[2] = (short)f2bf(acc[ct][2]); ov[3] = (short)f2bf(acc[ct][3]);
          *(bf16x4*)(p + ct * 16) = ov;
        }
      }
    } else if (node < NN) {
#pragma unroll
      for (int ct = 0; ct < 4; ++ct) {
        const float4 bv = *(const float4*)(bias + ct * 16 + quad * 4);
        const float o0 = acc[ct][0] + bv.x, o1 = acc[ct][1] + bv.y;
        const float o2 = acc[ct][2] + bv.z, o3 = acc[ct][3] + bv.w;
        if constexpr (ROOT_BF16) {
          unsigned short* p = (unsigned short*)root_out + (size_t)node * 64 + ct * 16 + quad * 4;
          bf16x4 ov;
          ov[0] = (short)f2bf(o0); ov[1] = (short)f2bf(o1);
          ov[2] = (short)f2bf(o2); ov[3] = (short)f2bf(o3);
          *(bf16x4*)p = ov;
        } else {
          float* p = (float*)root_out + (size_t)node * 64 + ct * 16 + quad * 4;
          *(float4*)p = make_float4(o0, o1, o2, o3);
        }
      }
    }
    __syncthreads();
  }
}

// ---------------- fused dispatch: append interleaved with gemm1 -------------
// blockIdx%3==2 -> append (391 of them, ids bx/3); others -> gemm
// (id = bx - (appends before bx) = bx - (bx+1)/3).
__global__ void __launch_bounds__(256) fused_append_gemm1(
    const int* __restrict__ src, const int* __restrict__ dst,
    const int* __restrict__ et, int* __restrict__ bcur,
    unsigned* __restrict__ brecs,
    const float* __restrict__ A, const unsigned short* __restrict__ Wt,
    const float* __restrict__ bias, unsigned short* __restrict__ xw,
    unsigned short* __restrict__ hroot) {
  extern __shared__ char smem[];
  const int bx = (int)blockIdx.x;
  if (bx % 3 == 2 && bx / 3 < NAPP)
    append_body(smem, bx / 3, src, dst, et, bcur, brecs);
  else
    gemm_body<FIN, true, true>(smem, bx - (bx + 1) / 3, A, Wt, bias, xw, hroot);
}

__global__ void __launch_bounds__(256) gemm_l2(
    const unsigned short* __restrict__ A, const unsigned short* __restrict__ Wt,
    const float* __restrict__ bias, unsigned short* __restrict__ xw,
    float* __restrict__ out) {
  extern __shared__ char smem[];
  gemm_body<FH, false, false>(smem, (int)blockIdx.x, A, Wt, bias, xw, out);
}

// ---------------- aggregation: one wave/dst, 8 gathers in flight ------------
// lane = e(3b) | l8(3b). Record: cnt<<25 | sv<<9 | r<<6 -> addr = rec & mask.
// Unconditional clamped gathers (R14 style). RELU_BF16: layer-1 (root bf16,
// out bf16+relu); else layer-2 (root f32, out f32; root may alias out).
template <bool RELU_BF16>
__global__ void __launch_bounds__(256) agg_csr(
    const int* __restrict__ row_start, const int* __restrict__ deg,
    const unsigned* __restrict__ recs, const unsigned short* __restrict__ xw,
    const void* __restrict__ rootv,
    float* __restrict__ out_f32, unsigned short* __restrict__ out_b16) {
  const int gid  = blockIdx.x * blockDim.x + threadIdx.x;
  const int lane = gid & 63;
  const int d    = gid >> 6;
  if (d >= NN) return;
  const int e  = lane >> 3;
  const int l8 = lane & 7;
  const int base = row_start[d];
  const int n    = deg[d];
  const unsigned* po = recs + base;
  const unsigned short* xp = xw + l8 * 8;
  float a[8] = {};

  int i0 = 0;
  for (; i0 + 32 < n; i0 += 64) {
    unsigned rr[8];
#pragma unroll
    for (int sl = 0; sl < 8; ++sl) {
      const int i = i0 + e + 8 * sl;
      rr[sl] = (i < n) ? po[i] : 0u;
    }
    bf16x8 vv[8];
#pragma unroll
    for (int sl = 0; sl < 8; ++sl) {
      const unsigned u = min(rr[sl] & 0x01FFFFFFu, XWMAX);
      vv[sl] = *(const bf16x8*)(xp + u);
    }
#pragma unroll
    for (int sl = 0; sl < 8; ++sl) {
      float w = __builtin_amdgcn_rcpf((float)(rr[sl] >> 25));
      if (i0 + e + 8 * sl >= n) w = 0.f;
#pragma unroll
      for (int q = 0; q < 8; ++q) a[q] += bf2f((unsigned short)vv[sl][q]) * w;
    }
  }
  if (i0 < n) {
    unsigned rr[4];
#pragma unroll
    for (int sl = 0; sl < 4; ++sl) {
      const int i = i0 + e + 8 * sl;
      rr[sl] = (i < n) ? po[i] : 0u;
    }
    bf16x8 vv[4];
#pragma unroll
    for (int sl = 0; sl < 4; ++sl) {
      const unsigned u = min(rr[sl] & 0x01FFFFFFu, XWMAX);
      vv[sl] = *(const bf16x8*)(xp + u);
    }
#pragma unroll
    for (int sl = 0; sl < 4; ++sl) {
      float w = __builtin_amdgcn_rcpf((float)(rr[sl] >> 25));
      if (i0 + e + 8 * sl >= n) w = 0.f;
#pragma unroll
      for (int q = 0; q < 8; ++q) a[q] += bf2f((unsigned short)vv[sl][q]) * w;
    }
  }

#pragma unroll
  for (int q = 0; q < 8; ++q) {
    a[q] += __shfl_xor(a[q], 8, 64);
    a[q] += __shfl_xor(a[q], 16, 64);
    a[q] += __shfl_xor(a[q], 32, 64);
  }

  if (e == 0) {
    float r[8];
    if constexpr (RELU_BF16) {
      const bf16x8 rv = *(const bf16x8*)((const unsigned short*)rootv + (size_t)d * 64 + l8 * 8);
#pragma unroll
      for (int q = 0; q < 8; ++q) r[q] = bf2f((unsigned short)rv[q]);
    } else {
      const float4 r0 = *(const float4*)((const float*)rootv + (size_t)d * 64 + l8 * 8);
      const float4 r1 = *(const float4*)((const float*)rootv + (size_t)d * 64 + l8 * 8 + 4);
      r[0] = r0.x; r[1] = r0.y; r[2] = r0.z; r[3] = r0.w;
      r[4] = r1.x; r[5] = r1.y; r[6] = r1.z; r[7] = r1.w;
    }
    float o[8];
#pragma unroll
    for (int q = 0; q < 8; ++q) o[q] = r[q] + a[q];
    if (RELU_BF16) {
      bf16x8 ov;
#pragma unroll
      for (int q = 0; q < 8; ++q) ov[q] = (short)f2bf(fmaxf(o[q], 0.f));
      *(bf16x8*)(out_b16 + (size_t)d * 64 + l8 * 8) = ov;
    } else {
      *(float4*)(out_f32 + (size_t)d * 64 + l8 * 8)     = make_float4(o[0], o[1], o[2], o[3]);
      *(float4*)(out_f32 + (size_t)d * 64 + l8 * 8 + 4) = make_float4(o[4], o[5], o[6], o[7]);
    }
  }
}

extern "C" void kernel_launch(void* const* d_in, const int* in_sizes, int n_in,
                              void* d_out, int out_size, void* d_ws, size_t ws_size,
                              hipStream_t stream) {
  const float* x   = (const float*)d_in[0];
  const int*   ei  = (const int*)d_in[1];
  const int*   et  = (const int*)d_in[2];
  const float* W1r = (const float*)d_in[3];
  const float* W1o = (const float*)d_in[4];
  const float* b1  = (const float*)d_in[5];
  const float* W2r = (const float*)d_in[6];
  const float* W2o = (const float*)d_in[7];
  const float* b2  = (const float*)d_in[8];
  float* out = (float*)d_out;

  const int* src = ei;
  const int* dst = ei + NE;

  char* ws = (char*)d_ws;
  size_t off = 0;
  auto alloc = [&](size_t bytes) {
    void* p = ws + off; off += (bytes + 255) & ~(size_t)255; return p;
  };
  int*   bcur      = (int*)alloc((size_t)NB * 4);
  int*   row_start = (int*)alloc((size_t)NN * 4);
  int*   deg       = (int*)alloc((size_t)NN * 4);
  unsigned* brecs  = (unsigned*)alloc((size_t)NB * CAP * 4);                //  9.6 MB
  unsigned* offs   = (unsigned*)alloc((size_t)NB * CAP * 4);                //  9.6 MB
  unsigned short* xw    = (unsigned short*)alloc((size_t)NN * NR * 64 * 2); // 51.2 MB
  unsigned short* hb    = (unsigned short*)alloc((size_t)NN * FH * 2);      //  6.4 MB
  unsigned short* hroot = (unsigned short*)alloc((size_t)NN * 64 * 2);      //  6.4 MB
  unsigned short* Wt1   = (unsigned short*)alloc((size_t)(NR + 1) * 64 * FIN * 2);
  unsigned short* Wt2   = (unsigned short*)alloc((size_t)(NR + 1) * 64 * FH * 2);

  const int nprep = (NR + 1) * 64 * (FIN + FH);
  prep<<<(nprep + 255) / 256, 256, 0, stream>>>(W1r, W1o, W2r, W2o, Wt1, Wt2, bcur);

  const int gemm_blocks = (NN + 63) / 64;              // 782
  const int agg_blocks  = (NN * 64 + 255) / 256;       // 12500
  constexpr int SM1 = CH * 8 + 4 * NB * 4 + 16;        // 39040 (>= gemm 34816)
  constexpr int SM2 = 2 * 64 * (FH + 8) * 2;           // 18432

  // Layer 1 transform || CSR append (interleaved roles), then finalize.
  fused_append_gemm1<<<NAPP + gemm_blocks, 256, SM1, stream>>>(
      src, dst, et, bcur, brecs, x, Wt1, b1, xw, hroot);
  bucket_finalize<<<NB, 256, 0, stream>>>(bcur, brecs, row_start, deg, offs);

  // Layer 1 aggregate, Layer 2 transform + aggregate (root aliases out).
  agg_csr<true><<<agg_blocks, 256, 0, stream>>>(row_start, deg, offs, xw, hroot, nullptr, hb);
  gemm_l2<<<gemm_blocks, 256, SM2, stream>>>(hb, Wt2, b2, xw, out);
  agg_csr<false><<<agg_blocks, 256, 0, stream>>>(row_start, deg, offs, xw, out, out, nullptr);
}

// Round 10
// 242.483 us; speedup vs baseline: 1.0390x; 1.0063x over previous
//
#include <hip/hip_runtime.h>

// RGCN: N=50000, E=1.6M, R=8, 128 -> 64 -> 64.
// R21 = R14 layer-1 VERBATIM (239.4us best) + layer-2 restructured to
// aggregate-then-transform:
//   - finalize additionally emits segs[d][r] = (abs_start<<8 | cnt) per
//     (dst, rel) segment (records already r-sorted within each row).
//   - agg2_sums: lane = (r,l8); each 8-lane group serially walks its rel
//     segment (4 gathers in flight), gather source = hb (6.4MB, L2-resident
//     vs 51.2MB random before). Writes mean[d][r][64] bf16 + copies h[d]
//     into slot 8 -> sums[d][576], one contiguous 1KB row per wave.
//   - gemm_final: out[d] = sums[d][0..575] @ W2stack[576][64] + b2, single
//     K=576 MFMA GEMM (no 9-group loop, no 51.2MB xw2 materialization).
// Mechanism: layer-2 HBM ~202->~140MB and the random gather becomes
// cache-resident; replaces agg2(42us)+gemm_l2(~18us).

constexpr int NN  = 50000;
constexpr int NE  = 1600000;
constexpr int NR  = 8;
constexpr int FIN = 128;
constexpr int FH  = 64;

constexpr int BSH = 7;                       // 128 dst nodes per bucket
constexpr int BN  = 1 << BSH;
constexpr int NB  = (NN + BN - 1) >> BSH;    // 391
constexpr int CAP = 6144;                    // bucket capacity (load ~4092±64)
constexpr int CH  = 4096;                    // edges per append block
constexpr int NAPP = (NE + CH - 1) / CH;     // 391 append blocks
constexpr unsigned XWMAX = (unsigned)(NN - 1) * (NR * 64) + (NR - 1) * 64;
constexpr int K2  = 576;                     // 8 rel * 64 + 64 root
constexpr int K2P = 584;                     // LDS row pitch

typedef __attribute__((ext_vector_type(8))) short bf16x8;
typedef __attribute__((ext_vector_type(4))) float f32x4;

__device__ __forceinline__ unsigned short f2bf(float f) {
  unsigned u = __float_as_uint(f);
  u = (u + 0x7fff + ((u >> 16) & 1)) >> 16;   // RNE
  return (unsigned short)u;
}
__device__ __forceinline__ float bf2f(unsigned short b) {
  return __uint_as_float(((unsigned)b) << 16);
}
__device__ __forceinline__ bool edge_ok(unsigned s, unsigned d, unsigned r) {
  return s < NN && d < NN && r < NR;
}

// ---------------- CSR build: append (device body, LDS via pointer) ----------
// LDS: stage[CH] (32768B) | h[NB] | gbase[NB] | sbase[NB] | scur[NB] | wtot[4]
__device__ void append_body(char* smem, int bx,
                            const int* __restrict__ src,
                            const int* __restrict__ dst,
                            const int* __restrict__ et,
                            int* __restrict__ bcur,
                            unsigned* __restrict__ brecs) {
  uint2* stage = (uint2*)smem;
  int* h     = (int*)(smem + (size_t)CH * 8);
  int* gbase = h + NB;
  int* sbase = gbase + NB;
  int* scur  = sbase + NB;
  int* wtot  = scur + NB;

  const int t  = threadIdx.x;
  const int c0 = bx * CH;
  const int m  = min(CH, NE - c0);

  for (int i = t; i < NB; i += 256) h[i] = 0;
  __syncthreads();

  for (int i = t; i < m; i += 256) {
    const unsigned s = (unsigned)src[c0 + i];
    const unsigned d = (unsigned)dst[c0 + i];
    const unsigned r = (unsigned)et[c0 + i];
    if (edge_ok(s, d, r)) atomicAdd(&h[d >> BSH], 1);
  }
  __syncthreads();

  const int v0 = (2 * t < NB) ? h[2 * t] : 0;
  const int v1 = (2 * t + 1 < NB) ? h[2 * t + 1] : 0;
  if (2 * t < NB     && v0) gbase[2 * t]     = atomicAdd(&bcur[2 * t], v0);
  if (2 * t + 1 < NB && v1) gbase[2 * t + 1] = atomicAdd(&bcur[2 * t + 1], v1);
  const int s = v0 + v1;
  int incl = s;
#pragma unroll
  for (int o = 1; o < 64; o <<= 1) {
    int u = __shfl_up(incl, o, 64);
    if ((t & 63) >= o) incl += u;
  }
  if ((t & 63) == 63) wtot[t >> 6] = incl;
  __syncthreads();
  int wo = 0;
  for (int w = 0; w < (t >> 6); ++w) wo += wtot[w];
  const int e = wo + incl - s;
  if (2 * t < NB)     { sbase[2 * t] = e;          scur[2 * t] = e; }
  if (2 * t + 1 < NB) { sbase[2 * t + 1] = e + v0; scur[2 * t + 1] = e + v0; }
  __syncthreads();

  for (int i = t; i < m; i += 256) {
    const unsigned sv = (unsigned)src[c0 + i];
    const unsigned d  = (unsigned)dst[c0 + i];
    const unsigned r  = (unsigned)et[c0 + i];
    if (edge_ok(sv, d, r)) {
      const int p = atomicAdd(&scur[d >> BSH], 1);
      if (p < CH) stage[p] = make_uint2((sv << 10) | (((unsigned)d & (BN - 1)) << 3) | r, d);
    }
  }
  __syncthreads();

  const int M = min(sbase[NB - 1] + h[NB - 1], CH);
  for (int j = t; j < M; j += 256) {
    const uint2 rec = stage[j];
    const int b = (int)(rec.y >> BSH);
    const int idx = min(gbase[b] + (j - sbase[b]), NB * CAP - 1);
    brecs[idx] = rec.x;
  }
}

// ---------------- CSR build: finalize ----------------
// Records: cnt<<25 | sv<<9 | r<<6 (weight 1/cnt via v_rcp in agg1).
// NEW: segs[d*8+r] = (absolute segment start << 8) | min(cnt,255) for the
// layer-2 per-(d,r) segment walk.
__global__ void __launch_bounds__(256) bucket_finalize(
    const int* __restrict__ bcur, const unsigned* __restrict__ brecs,
    int* __restrict__ row_start, int* __restrict__ deg,
    unsigned* __restrict__ recs, unsigned* __restrict__ segs) {
  const int b    = blockIdx.x;
  const int base = b * CAP;
  const int m    = min(bcur[b] - base, CAP);
  const int d0   = b << BSH;
  __shared__ int cnt[BN * NR];
  __shared__ int curs[BN * NR];
  __shared__ int wtot[4];
  const int t = threadIdx.x;

  for (int i = t; i < BN * NR; i += 256) cnt[i] = 0;
  __syncthreads();
  for (int i = t; i < m; i += 256) {
    const unsigned rec = brecs[base + i];
    const int dl = (int)((rec >> 3) & (BN - 1));
    const int r  = (int)(rec & 7);
    atomicAdd(&cnt[dl * NR + r], 1);
  }
  __syncthreads();

  const int c0 = cnt[t * 4], c1 = cnt[t * 4 + 1], c2 = cnt[t * 4 + 2], c3 = cnt[t * 4 + 3];
  const int s = c0 + c1 + c2 + c3;
  int incl = s;
#pragma unroll
  for (int o = 1; o < 64; o <<= 1) {
    int u = __shfl_up(incl, o, 64);
    if ((t & 63) >= o) incl += u;
  }
  if ((t & 63) == 63) wtot[t >> 6] = incl;
  __syncthreads();
  int wo = 0;
  for (int w = 0; w < (t >> 6); ++w) wo += wtot[w];
  const int e = wo + incl - s;
  curs[t * 4]     = e;
  curs[t * 4 + 1] = e + c0;
  curs[t * 4 + 2] = e + c0 + c1;
  curs[t * 4 + 3] = e + c0 + c1 + c2;
  __syncthreads();

  if (t < BN) {
    const int d = d0 + t;
    if (d < NN) {
      const int start = curs[t * NR];
      const int end   = (t == BN - 1) ? m : curs[(t + 1) * NR];
      row_start[d] = base + start;
      deg[d]       = end - start;
#pragma unroll
      for (int r = 0; r < NR; ++r) {
        const unsigned st = (unsigned)(base + curs[t * NR + r]);
        const unsigned cn = (unsigned)min(cnt[t * NR + r], 255);
        segs[(size_t)d * NR + r] = (st << 8) | cn;
      }
    }
  }
  __syncthreads();

  for (int i = t; i < m; i += 256) {
    const unsigned rec = brecs[base + i];
    const int dl = (int)((rec >> 3) & (BN - 1));
    const int r  = (int)(rec & 7);
    const unsigned sv = rec >> 10;
    const int p  = atomicAdd(&curs[dl * NR + r], 1);
    const unsigned cn = (unsigned)min(cnt[dl * NR + r], 127);
    recs[base + min(p, CAP - 1)] = (cn << 25) | (sv << 9) | ((unsigned)r << 6);
  }
}

// ---------------- prep: bcur init + weights -> bf16 transposed ----------------
// Wt1: [g][n][k] for g<NR rel + g==NR root (K=FIN), as R14.
// Wt2b: STACKED [n][576]: k = r*64+kk (r<8, W2_r) then 512+kk (W2_root).
__global__ void prep(const float* __restrict__ W1r, const float* __restrict__ W1o,
                     const float* __restrict__ W2r, const float* __restrict__ W2o,
                     unsigned short* __restrict__ Wt1,
                     unsigned short* __restrict__ Wt2b,
                     int* __restrict__ bcur) {
  const int i  = blockIdx.x * blockDim.x + threadIdx.x;
  if (i < NB) bcur[i] = i * CAP;
  const int n1 = (NR + 1) * 64 * FIN;
  const int n2 = 64 * K2;
  if (i < n1) {
    const int g = i / (64 * FIN), rem = i % (64 * FIN);
    const int n = rem / FIN, k = rem % FIN;
    const float* W = (g < NR) ? (W1r + (size_t)g * FIN * 64) : W1o;
    Wt1[i] = f2bf(W[k * 64 + n]);
  } else if (i < n1 + n2) {
    const int j = i - n1;
    const int n = j / K2, c = j % K2;
    float v;
    if (c < 512) {
      const int r = c >> 6, kk = c & 63;
      v = W2r[((size_t)r * 64 + kk) * 64 + n];
    } else {
      const int kk = c - 512;
      v = W2o[(size_t)kk * 64 + n];
    }
    Wt2b[j] = f2bf(v);
  }
}

// ---------------- MFMA GEMM body (R14 verbatim): A in regs, B-dbuf LDS ------
template <int K, bool A_FP32>
__device__ void gemm_body(char* smem, int bx,
                          const void* __restrict__ Av,
                          const unsigned short* __restrict__ Wt,
                          const float* __restrict__ bias,
                          unsigned short* __restrict__ xw,
                          float* __restrict__ root_out) {
  constexpr int KP  = K + 8;
  constexpr int NCH = 64 * (K / 8) / 256;
  constexpr int NKC = K / 32;
  unsigned short* Bs0 = (unsigned short*)smem;   // dbuf halves: 2 x 64*KP
  const int n0  = bx * 64;
  const int tid = threadIdx.x;
  const int wave = tid >> 6, lane = tid & 63;
  const int i16 = lane & 15, quad = lane >> 4;
  const int r0 = wave * 16 + i16;
  const int arow = n0 + r0;

  bf16x8 afrag[NKC];
  if constexpr (A_FP32) {
    const float* A = (const float*)Av;
#pragma unroll
    for (int kc = 0; kc < NKC; ++kc) {
      bf16x8 v = {};
      if (arow < NN) {
        const float* p = A + (size_t)arow * K + kc * 32 + quad * 8;
        const float4 f0 = *(const float4*)p;
        const float4 f1 = *(const float4*)(p + 4);
        v[0] = f2bf(f0.x); v[1] = f2bf(f0.y); v[2] = f2bf(f0.z); v[3] = f2bf(f0.w);
        v[4] = f2bf(f1.x); v[5] = f2bf(f1.y); v[6] = f2bf(f1.z); v[7] = f2bf(f1.w);
      }
      afrag[kc] = v;
    }
  } else {
    const unsigned short* A = (const unsigned short*)Av;
#pragma unroll
    for (int kc = 0; kc < NKC; ++kc) {
      bf16x8 v = {};
      if (arow < NN) v = *(const bf16x8*)(A + (size_t)arow * K + kc * 32 + quad * 8);
      afrag[kc] = v;
    }
  }

  for (int c = 0; c < NCH; ++c) {
    const int idx = tid + c * 256;
    const int row = idx / (K / 8), kp = (idx % (K / 8)) * 8;
    *(bf16x8*)(Bs0 + row * KP + kp) = *(const bf16x8*)(Wt + idx * 8);
  }
  __syncthreads();

  for (int g = 0; g <= NR; ++g) {
    const int buf = g & 1;
    unsigned short* Bc = Bs0 + buf * 64 * KP;
    unsigned short* Bn = Bs0 + (buf ^ 1) * 64 * KP;
    bf16x8 breg[NCH];
    if (g < NR) {
      const unsigned short* Wn = Wt + (size_t)(g + 1) * 64 * K;
#pragma unroll
      for (int c = 0; c < NCH; ++c) breg[c] = *(const bf16x8*)(Wn + (tid + c * 256) * 8);
    }

    f32x4 acc[4] = {};
#pragma unroll
    for (int kc = 0; kc < NKC; ++kc) {
      const int k0 = kc * 32 + quad * 8;
      const bf16x8 a0 = afrag[kc];
      const bf16x8 b0 = *(const bf16x8*)(Bc + (i16)      * KP + k0);
      const bf16x8 b1 = *(const bf16x8*)(Bc + (i16 + 16) * KP + k0);
      const bf16x8 b2 = *(const bf16x8*)(Bc + (i16 + 32) * KP + k0);
      const bf16x8 b3 = *(const bf16x8*)(Bc + (i16 + 48) * KP + k0);
      acc[0] = __builtin_amdgcn_mfma_f32_16x16x32_bf16(a0, b0, acc[0], 0, 0, 0);
      acc[1] = __builtin_amdgcn_mfma_f32_16x16x32_bf16(a0, b1, acc[1], 0, 0, 0);
      acc[2] = __builtin_amdgcn_mfma_f32_16x16x32_bf16(a0, b2, acc[2], 0, 0, 0);
      acc[3] = __builtin_amdgcn_mfma_f32_16x16x32_bf16(a0, b3, acc[3], 0, 0, 0);
    }

    if (g < NR) {
#pragma unroll
      for (int c = 0; c < NCH; ++c) {
        const int idx = tid + c * 256;
        const int row = idx / (K / 8), kp = (idx % (K / 8)) * 8;
        *(bf16x8*)(Bn + row * KP + kp) = breg[c];
      }
#pragma unroll
      for (int reg = 0; reg < 4; ++reg) {
        const int n = n0 + wave * 16 + quad * 4 + reg;
        if (n >= NN) continue;
        unsigned short* p = xw + (size_t)n * (NR * 64) + g * 64 + i16;
#pragma unroll
        for (int ct = 0; ct < 4; ++ct) p[ct * 16] = f2bf(acc[ct][reg]);
      }
    } else {
      float bv[4];
#pragma unroll
      for (int ct = 0; ct < 4; ++ct) bv[ct] = bias[ct * 16 + i16];
#pragma unroll
      for (int reg = 0; reg < 4; ++reg) {
        const int n = n0 + wave * 16 + quad * 4 + reg;
        if (n >= NN) continue;
        float* p = root_out + (size_t)n * 64 + i16;
#pragma unroll
        for (int ct = 0; ct < 4; ++ct) p[ct * 16] = acc[ct][reg] + bv[ct];
      }
    }
    __syncthreads();
  }
}

// ---------------- fused dispatch: append interleaved with gemm1 -------------
__global__ void __launch_bounds__(256) fused_append_gemm1(
    const int* __restrict__ src, const int* __restrict__ dst,
    const int* __restrict__ et, int* __restrict__ bcur,
    unsigned* __restrict__ brecs,
    const float* __restrict__ A, const unsigned short* __restrict__ Wt,
    const float* __restrict__ bias, unsigned short* __restrict__ xw,
    float* __restrict__ root_out) {
  extern __shared__ char smem[];
  const int bx = (int)blockIdx.x;
  if (bx % 3 == 2 && bx / 3 < NAPP)
    append_body(smem, bx / 3, src, dst, et, bcur, brecs);
  else
    gemm_body<FIN, true>(smem, bx - (bx + 1) / 3, A, Wt, bias, xw, root_out);
}

// ---------------- layer-1 aggregation (R14 verbatim): one wave/dst ----------
__global__ void __launch_bounds__(256) agg1(
    const int* __restrict__ row_start, const int* __restrict__ deg,
    const unsigned* __restrict__ recs, const unsigned short* __restrict__ xw,
    const float* __restrict__ root, unsigned short* __restrict__ out_b16) {
  const int gid  = blockIdx.x * blockDim.x + threadIdx.x;
  const int lane = gid & 63;
  const int d    = gid >> 6;
  if (d >= NN) return;
  const int e  = lane >> 3;
  const int l8 = lane & 7;
  const int base = row_start[d];
  const int n    = deg[d];
  const unsigned* po = recs + base;
  const unsigned short* xp = xw + l8 * 8;
  float a[8] = {};

  int i0 = 0;
  for (; i0 + 32 < n; i0 += 64) {
    unsigned rr[8];
#pragma unroll
    for (int sl = 0; sl < 8; ++sl) {
      const int i = i0 + e + 8 * sl;
      rr[sl] = (i < n) ? po[i] : 0u;
    }
    bf16x8 vv[8];
#pragma unroll
    for (int sl = 0; sl < 8; ++sl) {
      const unsigned u = min(rr[sl] & 0x01FFFFFFu, XWMAX);
      vv[sl] = *(const bf16x8*)(xp + u);
    }
#pragma unroll
    for (int sl = 0; sl < 8; ++sl) {
      float w = __builtin_amdgcn_rcpf((float)(rr[sl] >> 25));
      if (i0 + e + 8 * sl >= n) w = 0.f;
#pragma unroll
      for (int q = 0; q < 8; ++q) a[q] += bf2f((unsigned short)vv[sl][q]) * w;
    }
  }
  if (i0 < n) {
    unsigned rr[4];
#pragma unroll
    for (int sl = 0; sl < 4; ++sl) {
      const int i = i0 + e + 8 * sl;
      rr[sl] = (i < n) ? po[i] : 0u;
    }
    bf16x8 vv[4];
#pragma unroll
    for (int sl = 0; sl < 4; ++sl) {
      const unsigned u = min(rr[sl] & 0x01FFFFFFu, XWMAX);
      vv[sl] = *(const bf16x8*)(xp + u);
    }
#pragma unroll
    for (int sl = 0; sl < 4; ++sl) {
      float w = __builtin_amdgcn_rcpf((float)(rr[sl] >> 25));
      if (i0 + e + 8 * sl >= n) w = 0.f;
#pragma unroll
      for (int q = 0; q < 8; ++q) a[q] += bf2f((unsigned short)vv[sl][q]) * w;
    }
  }

#pragma unroll
  for (int q = 0; q < 8; ++q) {
    a[q] += __shfl_xor(a[q], 8, 64);
    a[q] += __shfl_xor(a[q], 16, 64);
    a[q] += __shfl_xor(a[q], 32, 64);
  }

  if (e == 0) {
    const float4 r0 = *(const float4*)(root + (size_t)d * 64 + l8 * 8);
    const float4 r1 = *(const float4*)(root + (size_t)d * 64 + l8 * 8 + 4);
    const float o[8] = {r0.x + a[0], r0.y + a[1], r0.z + a[2], r0.w + a[3],
                        r1.x + a[4], r1.y + a[5], r1.z + a[6], r1.w + a[7]};
    bf16x8 ov;
#pragma unroll
    for (int q = 0; q < 8; ++q) ov[q] = (short)f2bf(fmaxf(o[q], 0.f));
    *(bf16x8*)(out_b16 + (size_t)d * 64 + l8 * 8) = ov;
  }
}

// ---------------- layer-2 per-(d,r) mean aggregation ------------------------
// One wave per dst. lane = r(3b) | l8(3b): each 8-lane group walks its own
// rel segment (records r-sorted within the row), gathering h rows from hb
// (6.4MB, L2-resident). 4 gathers in flight; no cross-lane reduction.
// Output: sums[d][576] bf16 = [mean_{d,0..7} | h_d].
__global__ void __launch_bounds__(256) agg2_sums(
    const unsigned* __restrict__ segs, const unsigned* __restrict__ recs,
    const unsigned short* __restrict__ hb, unsigned short* __restrict__ sums) {
  const int gid  = blockIdx.x * blockDim.x + threadIdx.x;
  const int lane = gid & 63;
  const int d    = gid >> 6;
  if (d >= NN) return;
  const int r  = lane >> 3;
  const int l8 = lane & 7;
  const unsigned sg = segs[(size_t)d * NR + r];
  const int start = (int)(sg >> 8);
  const int len   = (int)(sg & 255u);
  const unsigned* po = recs + start;
  const unsigned short* hp = hb + l8 * 8;
  float a[8] = {};

  for (int j = 0; j < len; j += 4) {
    unsigned rr[4];
#pragma unroll
    for (int sl = 0; sl < 4; ++sl)
      rr[sl] = (j + sl < len) ? po[j + sl] : 0u;
    bf16x8 vv[4];
#pragma unroll
    for (int sl = 0; sl < 4; ++sl) {
      const unsigned sv = (rr[sl] >> 9) & 0xFFFFu;   // sv < NN by construction
      vv[sl] = *(const bf16x8*)(hp + sv * 64);
    }
#pragma unroll
    for (int sl = 0; sl < 4; ++sl) {
      const float wk = (j + sl < len) ? 1.f : 0.f;
#pragma unroll
      for (int q = 0; q < 8; ++q) a[q] += bf2f((unsigned short)vv[sl][q]) * wk;
    }
  }

  const float w = (len > 0) ? __builtin_amdgcn_rcpf((float)len) : 0.f;
  bf16x8 ov;
#pragma unroll
  for (int q = 0; q < 8; ++q) ov[q] = (short)f2bf(a[q] * w);
  *(bf16x8*)(sums + (size_t)d * K2 + r * 64 + l8 * 8) = ov;

  if (lane < 8) {   // copy h[d] into slot 8 (root operand of the K=576 gemm)
    const bf16x8 hv = *(const bf16x8*)(hb + (size_t)d * 64 + lane * 8);
    *(bf16x8*)(sums + (size_t)d * K2 + 512 + lane * 8) = hv;
  }
}

// ---------------- final K=576 GEMM: out = sums @ W2stack + b2 ---------------
// Swapped MFMA (verified R15/R20): lane&15 = node, ct*16+quad*4+reg = feat.
__global__ void __launch_bounds__(256) gemm_final(
    const unsigned short* __restrict__ A,      // sums [NN][576]
    const unsigned short* __restrict__ Wt,     // [64][576] stacked
    const float* __restrict__ bias, float* __restrict__ out) {
  __shared__ unsigned short Bs[64 * K2P];      // 74752 B
  const int tid = threadIdx.x;
  const int wave = tid >> 6, lane = tid & 63;
  const int i16 = lane & 15, quad = lane >> 4;
  const int n0 = (int)blockIdx.x * 64;
  const int node = n0 + wave * 16 + i16;

  // stage B: 64*576/8 = 4608 chunks, 18 per thread
#pragma unroll
  for (int c = 0; c < 18; ++c) {
    const int idx = tid + c * 256;
    const int row = idx / 72, kp = (idx % 72) * 8;
    *(bf16x8*)(Bs + row * K2P + kp) = *(const bf16x8*)(Wt + idx * 8);
  }

  bf16x8 afrag[18];
#pragma unroll
  for (int kc = 0; kc < 18; ++kc) {
    bf16x8 v = {};
    if (node < NN) v = *(const bf16x8*)(A + (size_t)node * K2 + kc * 32 + quad * 8);
    afrag[kc] = v;
  }
  __syncthreads();

  f32x4 acc[4] = {};
#pragma unroll
  for (int kc = 0; kc < 18; ++kc) {
    const int k0 = kc * 32 + quad * 8;
    const bf16x8 a0 = afrag[kc];
    const bf16x8 b0 = *(const bf16x8*)(Bs + (i16)      * K2P + k0);
    const bf16x8 b1 = *(const bf16x8*)(Bs + (i16 + 16) * K2P + k0);
    const bf16x8 b2 = *(const bf16x8*)(Bs + (i16 + 32) * K2P + k0);
    const bf16x8 b3 = *(const bf16x8*)(Bs + (i16 + 48) * K2P + k0);
    acc[0] = __builtin_amdgcn_mfma_f32_16x16x32_bf16(b0, a0, acc[0], 0, 0, 0);
    acc[1] = __builtin_amdgcn_mfma_f32_16x16x32_bf16(b1, a0, acc[1], 0, 0, 0);
    acc[2] = __builtin_amdgcn_mfma_f32_16x16x32_bf16(b2, a0, acc[2], 0, 0, 0);
    acc[3] = __builtin_amdgcn_mfma_f32_16x16x32_bf16(b3, a0, acc[3], 0, 0, 0);
  }

  if (node < NN) {
#pragma unroll
    for (int ct = 0; ct < 4; ++ct) {
      const float4 bv = *(const float4*)(bias + ct * 16 + quad * 4);
      float* p = out + (size_t)node * 64 + ct * 16 + quad * 4;
      *(float4*)p = make_float4(acc[ct][0] + bv.x, acc[ct][1] + bv.y,
                                acc[ct][2] + bv.z, acc[ct][3] + bv.w);
    }
  }
}

extern "C" void kernel_launch(void* const* d_in, const int* in_sizes, int n_in,
                              void* d_out, int out_size, void* d_ws, size_t ws_size,
                              hipStream_t stream) {
  const float* x   = (const float*)d_in[0];
  const int*   ei  = (const int*)d_in[1];
  const int*   et  = (const int*)d_in[2];
  const float* W1r = (const float*)d_in[3];
  const float* W1o = (const float*)d_in[4];
  const float* b1  = (const float*)d_in[5];
  const float* W2r = (const float*)d_in[6];
  const float* W2o = (const float*)d_in[7];
  const float* b2  = (const float*)d_in[8];
  float* out = (float*)d_out;

  const int* src = ei;
  const int* dst = ei + NE;

  char* ws = (char*)d_ws;
  size_t off = 0;
  auto alloc = [&](size_t bytes) {
    void* p = ws + off; off += (bytes + 255) & ~(size_t)255; return p;
  };
  int*   bcur      = (int*)alloc((size_t)NB * 4);
  int*   row_start = (int*)alloc((size_t)NN * 4);
  int*   deg       = (int*)alloc((size_t)NN * 4);
  unsigned* segs   = (unsigned*)alloc((size_t)NN * NR * 4);                 //  1.6 MB
  unsigned* brecs  = (unsigned*)alloc((size_t)NB * CAP * 4);                //  9.6 MB
  unsigned* recs   = (unsigned*)alloc((size_t)NB * CAP * 4);                //  9.6 MB
  unsigned short* xw    = (unsigned short*)alloc((size_t)NN * NR * 64 * 2); // 51.2 MB
  unsigned short* hb    = (unsigned short*)alloc((size_t)NN * FH * 2);      //  6.4 MB
  float*          hroot = (float*)alloc((size_t)NN * 64 * 4);               // 12.8 MB
  unsigned short* sums  = (unsigned short*)alloc((size_t)NN * K2 * 2);      // 57.6 MB
  unsigned short* Wt1   = (unsigned short*)alloc((size_t)(NR + 1) * 64 * FIN * 2);
  unsigned short* Wt2b  = (unsigned short*)alloc((size_t)64 * K2 * 2);

  const int nprep = (NR + 1) * 64 * FIN + 64 * K2;
  prep<<<(nprep + 255) / 256, 256, 0, stream>>>(W1r, W1o, W2r, W2o, Wt1, Wt2b, bcur);

  const int gemm_blocks = (NN + 63) / 64;              // 782
  const int agg_blocks  = (NN * 64 + 255) / 256;       // 12500
  constexpr int SM1 = CH * 8 + 4 * NB * 4 + 16;        // 39040 (>= gemm 34816)

  // Layer 1 transform || CSR append (interleaved roles), then finalize.
  fused_append_gemm1<<<NAPP + gemm_blocks, 256, SM1, stream>>>(
      src, dst, et, bcur, brecs, x, Wt1, b1, xw, hroot);
  bucket_finalize<<<NB, 256, 0, stream>>>(bcur, brecs, row_start, deg, recs, segs);

  // Layer 1 aggregate, Layer 2 aggregate-then-transform.
  agg1<<<agg_blocks, 256, 0, stream>>>(row_start, deg, recs, xw, hroot, hb);
  agg2_sums<<<agg_blocks, 256, 0, stream>>>(segs, recs, hb, sums);
  gemm_final<<<gemm_blocks, 256, 0, stream>>>(sums, Wt2b, b2, out);
}